// Round 7
// baseline (148.047 us; speedup 1.0000x reference)
//
#include <hip/hip_runtime.h>
#include <hip/hip_fp16.h>

// EdgeNetwork: out[e] = MLP(concat(x[s], x[t], vp[batch[s]])), 48->8->8->8->1,
// LayerNorm+tanh between layers.
//
// R7 structure:
//   node_pre (N threads): per-node layer-1 partials, mean-centered, fp16
//     tables ya/yb ([N,8] each, 1.6 MB -> L2-resident).  h1 = ya'[s]+yb'[t]
//     is zero-mean -> LN1 skips the mean pass.
//   pack_kernel (1 block): packs W2/W3/b2/b3/g/be as __half2 into ws.
//   edge_main (E threads): layers 2/3 matmuls in packed fp16 (v_pk_fma_f16,
//     2 ops/instr); LN partial sums packed; mu/var/rsqrt + tanh in fp32.
//     tanh = 1 - 2/(e^{2v}+1) (exp form, proven absmax 7.8e-3 in R5).
//   No LDS anywhere (R6 post-mortem: table build + bank conflicts ate the win).

struct WPack {
    __half2 w2[32];    // w2[i*4+j2] = (W2[i][2*j2], W2[i][2*j2+1])
    __half2 w3[32];
    __half2 b2p[4], b3p[4];
    __half2 g1p[4], be1p[4];
    __half2 g2p[4], be2p[4];
    __half2 g3p[4], be3p[4];
};

typedef __attribute__((ext_vector_type(8))) _Float16 h8;

__device__ __forceinline__ float fast_tanh(float v) {
    float e = __expf(2.0f * v);
    return fmaf(-2.0f, __builtin_amdgcn_rcpf(e + 1.0f), 1.0f);
}

// ---------------- Kernel A: per-node layer-1 partials (fp16, centered) -------
__global__ __launch_bounds__(256) void node_pre_kernel(
    const float* __restrict__ x,      // [N,16]
    const int* __restrict__ batch,    // [N]
    const float* __restrict__ vp,     // [64,16]
    const float* __restrict__ W1,     // [48,8]
    const float* __restrict__ b1,     // [8]
    h8* __restrict__ ya16,            // [N]
    h8* __restrict__ yb16,            // [N]
    int N)
{
    int n = blockIdx.x * blockDim.x + threadIdx.x;
    if (n >= N) return;

    const float4* px = reinterpret_cast<const float4*>(x) + (size_t)n * 4;
    float4 x0 = px[0], x1 = px[1], x2 = px[2], x3 = px[3];
    int g = batch[n];
    const float4* pv = reinterpret_cast<const float4*>(vp) + (size_t)g * 4;
    float4 v0 = pv[0], v1 = pv[1], v2 = pv[2], v3 = pv[3];

    float xs[16] = {x0.x, x0.y, x0.z, x0.w, x1.x, x1.y, x1.z, x1.w,
                    x2.x, x2.y, x2.z, x2.w, x3.x, x3.y, x3.z, x3.w};
    float vs[16] = {v0.x, v0.y, v0.z, v0.w, v1.x, v1.y, v1.z, v1.w,
                    v2.x, v2.y, v2.z, v2.w, v3.x, v3.y, v3.z, v3.w};

    float ya[8], yb[8];
#pragma unroll
    for (int j = 0; j < 8; ++j) { ya[j] = b1[j]; yb[j] = 0.0f; }

#pragma unroll
    for (int i = 0; i < 16; ++i) {
        float vx = xs[i];
        float vv = vs[i];
#pragma unroll
        for (int j = 0; j < 8; ++j) {
            ya[j] = fmaf(vx, W1[i * 8 + j], ya[j]);
            ya[j] = fmaf(vv, W1[(32 + i) * 8 + j], ya[j]);
            yb[j] = fmaf(vx, W1[(16 + i) * 8 + j], yb[j]);
        }
    }

    float mua = 0.0f, mub = 0.0f;
#pragma unroll
    for (int j = 0; j < 8; ++j) { mua += ya[j]; mub += yb[j]; }
    mua *= 0.125f; mub *= 0.125f;

    h8 va, vb;
#pragma unroll
    for (int j = 0; j < 8; ++j) {
        va[j] = (_Float16)(ya[j] - mua);
        vb[j] = (_Float16)(yb[j] - mub);
    }
    ya16[n] = va;
    yb16[n] = vb;
}

// ---------------- Kernel P: pack fp16 weight constants into ws ---------------
__global__ void pack_kernel(
    const float* __restrict__ W2, const float* __restrict__ b2,
    const float* __restrict__ W3, const float* __restrict__ b3,
    const float* __restrict__ g1, const float* __restrict__ be1,
    const float* __restrict__ g2, const float* __restrict__ be2,
    const float* __restrict__ g3, const float* __restrict__ be3,
    WPack* __restrict__ wp)
{
    int t = threadIdx.x;
    if (t < 32) {
        wp->w2[t] = __floats2half2_rn(W2[2 * t], W2[2 * t + 1]);
        wp->w3[t] = __floats2half2_rn(W3[2 * t], W3[2 * t + 1]);
    }
    if (t < 4) {
        wp->b2p[t]  = __floats2half2_rn(b2[2 * t],  b2[2 * t + 1]);
        wp->b3p[t]  = __floats2half2_rn(b3[2 * t],  b3[2 * t + 1]);
        wp->g1p[t]  = __floats2half2_rn(g1[2 * t],  g1[2 * t + 1]);
        wp->be1p[t] = __floats2half2_rn(be1[2 * t], be1[2 * t + 1]);
        wp->g2p[t]  = __floats2half2_rn(g2[2 * t],  g2[2 * t + 1]);
        wp->be2p[t] = __floats2half2_rn(be2[2 * t], be2[2 * t + 1]);
        wp->g3p[t]  = __floats2half2_rn(g3[2 * t],  g3[2 * t + 1]);
        wp->be3p[t] = __floats2half2_rn(be3[2 * t], be3[2 * t + 1]);
    }
}

// ---------------- Kernel B: per-edge MLP, packed fp16 ------------------------
__global__ __launch_bounds__(256) void edge_main_kernel(
    const int* __restrict__ ei,       // [2,E]
    const uint4* __restrict__ ya16,   // [N] (8 fp16 each)
    const uint4* __restrict__ yb16,   // [N]
    const WPack* __restrict__ wp,
    const float* __restrict__ W4, const float* __restrict__ b4,
    float* __restrict__ out, int E)
{
    int e = blockIdx.x * blockDim.x + threadIdx.x;
    if (e >= E) return;

    int s = ei[e];
    int t = ei[E + e];

    uint4 ua = ya16[s];
    uint4 ub = yb16[t];
    __half2 v[4];
    {
        const __half2* ha = reinterpret_cast<const __half2*>(&ua);
        const __half2* hb2 = reinterpret_cast<const __half2*>(&ub);
#pragma unroll
        for (int k = 0; k < 4; ++k) v[k] = __hadd2(ha[k], hb2[k]);
    }

    // ---- LN1 (pre-centered: no mean pass) + tanh ----
    __half2 s2 = __hmul2(v[0], v[0]);
    s2 = __hfma2(v[1], v[1], s2);
    s2 = __hfma2(v[2], v[2], s2);
    s2 = __hfma2(v[3], v[3], s2);
    float ss = __low2float(s2) + __high2float(s2);
    float r = __builtin_amdgcn_rsqf(fmaf(ss, 0.125f, 1e-5f));
    __half2 rr2 = __floats2half2_rn(r, r);

    float th[8];
    __half2 hb[8];      // broadcast pairs (th[i], th[i]) for pk_fma
#pragma unroll
    for (int k = 0; k < 4; ++k) {
        __half2 rg  = __hmul2(rr2, wp->g1p[k]);
        __half2 arg = __hfma2(v[k], rg, wp->be1p[k]);
        float a0 = fast_tanh(__low2float(arg));
        float a1 = fast_tanh(__high2float(arg));
        th[2 * k] = a0; th[2 * k + 1] = a1;
        hb[2 * k]     = __floats2half2_rn(a0, a0);
        hb[2 * k + 1] = __floats2half2_rn(a1, a1);
    }

    // ---- layer 2 (packed fp16) + LN + tanh ----
    __half2 acc[4];
#pragma unroll
    for (int k = 0; k < 4; ++k) acc[k] = wp->b2p[k];
#pragma unroll
    for (int i = 0; i < 8; ++i) {
#pragma unroll
        for (int k = 0; k < 4; ++k)
            acc[k] = __hfma2(hb[i], wp->w2[i * 4 + k], acc[k]);
    }
    {
        __half2 sm2 = __hadd2(__hadd2(acc[0], acc[1]), __hadd2(acc[2], acc[3]));
        __half2 sq2 = __hmul2(acc[0], acc[0]);
        sq2 = __hfma2(acc[1], acc[1], sq2);
        sq2 = __hfma2(acc[2], acc[2], sq2);
        sq2 = __hfma2(acc[3], acc[3], sq2);
        float sm = __low2float(sm2) + __high2float(sm2);
        float sq = __low2float(sq2) + __high2float(sq2);
        float mu = sm * 0.125f;
        float var = fmaf(sq, 0.125f, -mu * mu);
        float rr = __builtin_amdgcn_rsqf(var + 1e-5f);
        __half2 rrp = __floats2half2_rn(rr, rr);
        float m = -mu * rr;
        __half2 mm2 = __floats2half2_rn(m, m);
#pragma unroll
        for (int k = 0; k < 4; ++k) {
            __half2 rg  = __hmul2(rrp, wp->g2p[k]);
            __half2 c   = __hfma2(mm2, wp->g2p[k], wp->be2p[k]);
            __half2 arg = __hfma2(acc[k], rg, c);
            float a0 = fast_tanh(__low2float(arg));
            float a1 = fast_tanh(__high2float(arg));
            th[2 * k] = a0; th[2 * k + 1] = a1;
            hb[2 * k]     = __floats2half2_rn(a0, a0);
            hb[2 * k + 1] = __floats2half2_rn(a1, a1);
        }
    }

    // ---- layer 3 (packed fp16) + LN + tanh ----
#pragma unroll
    for (int k = 0; k < 4; ++k) acc[k] = wp->b3p[k];
#pragma unroll
    for (int i = 0; i < 8; ++i) {
#pragma unroll
        for (int k = 0; k < 4; ++k)
            acc[k] = __hfma2(hb[i], wp->w3[i * 4 + k], acc[k]);
    }
    {
        __half2 sm2 = __hadd2(__hadd2(acc[0], acc[1]), __hadd2(acc[2], acc[3]));
        __half2 sq2 = __hmul2(acc[0], acc[0]);
        sq2 = __hfma2(acc[1], acc[1], sq2);
        sq2 = __hfma2(acc[2], acc[2], sq2);
        sq2 = __hfma2(acc[3], acc[3], sq2);
        float sm = __low2float(sm2) + __high2float(sm2);
        float sq = __low2float(sq2) + __high2float(sq2);
        float mu = sm * 0.125f;
        float var = fmaf(sq, 0.125f, -mu * mu);
        float rr = __builtin_amdgcn_rsqf(var + 1e-5f);
        __half2 rrp = __floats2half2_rn(rr, rr);
        float m = -mu * rr;
        __half2 mm2 = __floats2half2_rn(m, m);
#pragma unroll
        for (int k = 0; k < 4; ++k) {
            __half2 rg  = __hmul2(rrp, wp->g3p[k]);
            __half2 c   = __hfma2(mm2, wp->g3p[k], wp->be3p[k]);
            __half2 arg = __hfma2(acc[k], rg, c);
            th[2 * k]     = fast_tanh(__low2float(arg));
            th[2 * k + 1] = fast_tanh(__high2float(arg));
        }
    }

    // ---- layer 4 (fp32) ----
    float o = b4[0];
#pragma unroll
    for (int i = 0; i < 8; ++i) o = fmaf(th[i], W4[i], o);

    out[e] = o;
}

// ---------------- Fallback: monolithic fp32 (only if ws too small) ----------
__device__ __forceinline__ void ln_tanh8_full(float* h, const float* __restrict__ g,
                                              const float* __restrict__ be) {
    float sm = 0.0f, sq = 0.0f;
#pragma unroll
    for (int j = 0; j < 8; ++j) { sm += h[j]; sq = fmaf(h[j], h[j], sq); }
    float mu = sm * 0.125f;
    float var = fmaf(sq, 0.125f, -mu * mu);
    float rr = __builtin_amdgcn_rsqf(var + 1e-5f);
#pragma unroll
    for (int j = 0; j < 8; ++j)
        h[j] = fast_tanh(fmaf(h[j] - mu, rr * g[j], be[j]));
}

__global__ __launch_bounds__(256) void edge_net_fallback(
    const float* __restrict__ x, const int* __restrict__ ei,
    const float* __restrict__ vp, const int* __restrict__ batch,
    const float* __restrict__ W1, const float* __restrict__ b1,
    const float* __restrict__ g1, const float* __restrict__ be1,
    const float* __restrict__ W2, const float* __restrict__ b2,
    const float* __restrict__ g2, const float* __restrict__ be2,
    const float* __restrict__ W3, const float* __restrict__ b3,
    const float* __restrict__ g3, const float* __restrict__ be3,
    const float* __restrict__ W4, const float* __restrict__ b4,
    float* __restrict__ out, int E)
{
    int e = blockIdx.x * blockDim.x + threadIdx.x;
    if (e >= E) return;
    int s = ei[e], t = ei[E + e];
    int gb = batch[s];
    float in[48];
    const float4* ps = reinterpret_cast<const float4*>(x) + (size_t)s * 4;
    const float4* pt = reinterpret_cast<const float4*>(x) + (size_t)t * 4;
    const float4* pv = reinterpret_cast<const float4*>(vp) + (size_t)gb * 4;
#pragma unroll
    for (int q = 0; q < 4; ++q) {
        float4 a = ps[q];
        in[q*4+0]=a.x; in[q*4+1]=a.y; in[q*4+2]=a.z; in[q*4+3]=a.w;
    }
#pragma unroll
    for (int q = 0; q < 4; ++q) {
        float4 a = pt[q];
        in[16+q*4+0]=a.x; in[16+q*4+1]=a.y; in[16+q*4+2]=a.z; in[16+q*4+3]=a.w;
    }
#pragma unroll
    for (int q = 0; q < 4; ++q) {
        float4 a = pv[q];
        in[32+q*4+0]=a.x; in[32+q*4+1]=a.y; in[32+q*4+2]=a.z; in[32+q*4+3]=a.w;
    }
    float h[8];
#pragma unroll
    for (int j = 0; j < 8; ++j) h[j] = b1[j];
#pragma unroll
    for (int i = 0; i < 48; ++i) {
        float v = in[i];
#pragma unroll
        for (int j = 0; j < 8; ++j) h[j] = fmaf(v, W1[i*8+j], h[j]);
    }
    ln_tanh8_full(h, g1, be1);
    float h2[8];
#pragma unroll
    for (int j = 0; j < 8; ++j) h2[j] = b2[j];
#pragma unroll
    for (int i = 0; i < 8; ++i) {
        float v = h[i];
#pragma unroll
        for (int j = 0; j < 8; ++j) h2[j] = fmaf(v, W2[i*8+j], h2[j]);
    }
    ln_tanh8_full(h2, g2, be2);
    float h3[8];
#pragma unroll
    for (int j = 0; j < 8; ++j) h3[j] = b3[j];
#pragma unroll
    for (int i = 0; i < 8; ++i) {
        float v = h2[i];
#pragma unroll
        for (int j = 0; j < 8; ++j) h3[j] = fmaf(v, W3[i*8+j], h3[j]);
    }
    ln_tanh8_full(h3, g3, be3);
    float o = b4[0];
#pragma unroll
    for (int i = 0; i < 8; ++i) o = fmaf(h3[i], W4[i], o);
    out[e] = o;
}

extern "C" void kernel_launch(void* const* d_in, const int* in_sizes, int n_in,
                              void* d_out, int out_size, void* d_ws, size_t ws_size,
                              hipStream_t stream) {
    const float* x     = (const float*)d_in[0];
    const int*   ei    = (const int*)d_in[1];
    const float* vp    = (const float*)d_in[2];
    const int*   batch = (const int*)d_in[3];
    const float* W1  = (const float*)d_in[4];
    const float* b1  = (const float*)d_in[5];
    const float* g1  = (const float*)d_in[6];
    const float* be1 = (const float*)d_in[7];
    const float* W2  = (const float*)d_in[8];
    const float* b2  = (const float*)d_in[9];
    const float* g2  = (const float*)d_in[10];
    const float* be2 = (const float*)d_in[11];
    const float* W3  = (const float*)d_in[12];
    const float* b3  = (const float*)d_in[13];
    const float* g3  = (const float*)d_in[14];
    const float* be3 = (const float*)d_in[15];
    const float* W4  = (const float*)d_in[16];
    const float* b4  = (const float*)d_in[17];

    int E = in_sizes[1] / 2;    // edge_index [2,E]
    int N = in_sizes[3];        // batch [N]
    float* out = (float*)d_out;

    size_t tab_bytes = (size_t)N * 8 * sizeof(_Float16);   // 1.6 MB per table
    size_t need = 2 * tab_bytes + sizeof(WPack) + 64;
    if (ws_size >= need) {
        h8* ya16 = (h8*)d_ws;
        h8* yb16 = (h8*)((char*)d_ws + tab_bytes);
        WPack* wp = (WPack*)((char*)d_ws + 2 * tab_bytes);

        int blockA = 256;
        int gridA = (N + blockA - 1) / blockA;
        hipLaunchKernelGGL(node_pre_kernel, dim3(gridA), dim3(blockA), 0, stream,
                           x, batch, vp, W1, b1, ya16, yb16, N);
        hipLaunchKernelGGL(pack_kernel, dim3(1), dim3(64), 0, stream,
                           W2, b2, W3, b3, g1, be1, g2, be2, g3, be3, wp);
        int blockB = 256;
        int gridB = (E + blockB - 1) / blockB;
        hipLaunchKernelGGL(edge_main_kernel, dim3(gridB), dim3(blockB), 0, stream,
                           ei, (const uint4*)ya16, (const uint4*)yb16, wp,
                           W4, b4, out, E);
    } else {
        int block = 256;
        int grid = (E + block - 1) / block;
        hipLaunchKernelGGL(edge_net_fallback, dim3(grid), dim3(block), 0, stream,
                           x, ei, vp, batch,
                           W1, b1, g1, be1, W2, b2, g2, be2, W3, b3, g3, be3,
                           W4, b4, out, E);
    }
}